// Round 1
// baseline (1357.213 us; speedup 1.0000x reference)
//
#include <hip/hip_runtime.h>
#include <math.h>

// Shapes: b=2, T=15, Hn=256, D=128, P=64, PPP=4096, REC=3
// d_out layout (f32): x_e[983040] | x_h[983040] | x_p[31457280] | x_h_p[31457280]
#define XE_OFF   0
#define XH_OFF   983040
#define XP_OFF   1966080
#define XHP_OFF  33423360

// scratch inside x_h_p region (written last, so free until the final kernel)
#define SCR_COS  0        // 8192
#define SCR_SIN  8192     // 8192
#define SCR_Q    16384    // 65536
#define SCR_K    81920    // 65536
#define SCR_V    147456   // 983040
#define SCR_HA   1130496  // 983040
#define SCR_HB   2113536  // 983040  (ends at 3096576 < 31457280)

__global__ __launch_bounds__(256) void rope_tab_k(float* __restrict__ cosb,
                                                  float* __restrict__ sinb) {
    int i = blockIdx.x * 256 + threadIdx.x;   // 8192 entries = 256 pos x 32 j
    int n = i >> 5, j = i & 31;
    float inv = expf(-(float)j * 0.28782313662425573f);  // 10000^(-2j/64)
    float ang = (float)n * inv;
    cosb[i] = cosf(ang);
    sinb[i] = sinf(ang);
}

// Patch-embed GEMM with fused patch gather.
// A row m = (b*15+t)*256 + n ; feature f = py*64+px ; x[b,t,0,(n>>4)*64+py,(n&15)*64+px]
__global__ __launch_bounds__(256) void embed_k(const float* __restrict__ x,
                                               const float* __restrict__ Wemb,
                                               const float* __restrict__ bemb,
                                               float* __restrict__ xe) {
    __shared__ float A[16][64];
    int m0 = blockIdx.x * 16;
    int bt = m0 >> 8;            // 16 rows never cross a (b,t) boundary (256 % 16 == 0)
    int n0 = m0 & 255;
    const float* xbase = x + (size_t)bt * 1048576;
    int tx = threadIdx.x & 127, ty = threadIdx.x >> 7;
    float acc[8];
#pragma unroll
    for (int r = 0; r < 8; ++r) acc[r] = 0.f;

    for (int kc = 0; kc < 64; ++kc) {   // kc == py
        __syncthreads();
#pragma unroll
        for (int j = 0; j < 4; ++j) {
            int e = threadIdx.x + 256 * j;
            int r = e >> 6, k = e & 63;
            int n = n0 + r;
            A[r][k] = xbase[((n >> 4) * 64 + kc) * 1024 + (n & 15) * 64 + k];
        }
        __syncthreads();
#pragma unroll 8
        for (int k = 0; k < 64; ++k) {
            float bv = Wemb[(kc * 64 + k) * 128 + tx];
#pragma unroll
            for (int r = 0; r < 8; ++r)
                acc[r] = fmaf(A[2 * r + ty][k], bv, acc[r]);
        }
    }
    float bb = bemb[tx];
#pragma unroll
    for (int r = 0; r < 8; ++r)
        xe[(size_t)(m0 + 2 * r + ty) * 128 + tx] = acc[r] + bb;
}

// q/k (with RoPE) and v projections for one layer. grid = (b*256), block = 128 (=d)
__global__ __launch_bounds__(128) void qkv_k(const float* __restrict__ h,
                                             const float* __restrict__ Wq, const float* __restrict__ bq,
                                             const float* __restrict__ Wk, const float* __restrict__ bk,
                                             const float* __restrict__ Wv, const float* __restrict__ bv,
                                             const float* __restrict__ cosb, const float* __restrict__ sinb,
                                             float* __restrict__ q, float* __restrict__ k,
                                             float* __restrict__ v) {
    int bn = blockIdx.x;
    int b = bn >> 8, n = bn & 255;
    int d = threadIdx.x;
    float hv[15];
#pragma unroll
    for (int t = 0; t < 15; ++t)
        hv[t] = h[(((size_t)b * 15 + t) * 256 + n) * 128 + d];
    float qp = bq[0], kp = bk[0];
#pragma unroll
    for (int t = 0; t < 15; ++t) {
        qp = fmaf(hv[t], Wq[t], qp);
        kp = fmaf(hv[t], Wk[t], kp);
    }
    // RoPE on first 64 dims (pairs)
    float qpart = __shfl_xor(qp, 1);
    float kpart = __shfl_xor(kp, 1);
    float qo = qp, ko = kp;
    if (d < 64) {
        int j = d >> 1;
        float c = cosb[n * 32 + j], s = sinb[n * 32 + j];
        if (d & 1) { qo = fmaf(qp, c,  qpart * s); ko = fmaf(kp, c,  kpart * s); }
        else       { qo = fmaf(qp, c, -qpart * s); ko = fmaf(kp, c, -kpart * s); }
    }
    q[((size_t)b * 256 + n) * 128 + d] = qo;
    k[((size_t)b * 256 + n) * 128 + d] = ko;
#pragma unroll
    for (int c = 0; c < 15; ++c) {
        float a = bv[c];
#pragma unroll
        for (int t = 0; t < 15; ++t) a = fmaf(hv[t], Wv[c * 15 + t], a);
        v[(((size_t)b * 15 + c) * 256 + n) * 128 + d] = a;
    }
}

// Criss-cross attention + residual. grid = (b*256 = b,h), block = 128 (=w).
// Row (b,h,w): logits eH[g]=q*k[b,g,w] (g!=h), eW[u]=q*k[b,h,u]; softmax over 384;
// out[c] = gamma*(sum_g pH*v[b,c,g,w] + sum_u pW*v[b,c,h,u])/S + hin[b,c,h,w]
__global__ __launch_bounds__(128) void attn_k(const float* __restrict__ hin,
                                              const float* __restrict__ q,
                                              const float* __restrict__ k,
                                              const float* __restrict__ v,
                                              const float* __restrict__ gptr,
                                              float* __restrict__ hout) {
    __shared__ float klds[128];
    __shared__ float vlds[15][128];
    int bb = blockIdx.x >> 8, hh = blockIdx.x & 255;
    int w = threadIdx.x;
    const float* kb = k + (size_t)bb * 256 * 128;
    const float* vb = v + (size_t)bb * 15 * 256 * 128;
    float qs = q[((size_t)bb * 256 + hh) * 128 + w];
    klds[w] = kb[hh * 128 + w];
#pragma unroll
    for (int c = 0; c < 15; ++c)
        vlds[c][w] = vb[(c * 256 + hh) * 128 + w];
    __syncthreads();

    // pass 1: running max over all 384 logits
    float m = -3.4e38f;
    for (int g = 0; g < 256; ++g) {
        float lg = qs * kb[g * 128 + w];
        if (g != hh) m = fmaxf(m, lg);
    }
#pragma unroll 8
    for (int u = 0; u < 128; ++u)
        m = fmaxf(m, qs * klds[u]);

    // pass 2: exp + weighted accumulate
    float S = 0.f;
    float acc[15];
#pragma unroll
    for (int c = 0; c < 15; ++c) acc[c] = 0.f;
    for (int g = 0; g < 256; ++g) {
        if (g == hh) continue;
        float p = __expf(fmaf(qs, kb[g * 128 + w], -m));
        S += p;
        const float* vg = vb + g * 128 + w;
#pragma unroll
        for (int c = 0; c < 15; ++c)
            acc[c] = fmaf(p, vg[(size_t)c * 32768], acc[c]);
    }
#pragma unroll 4
    for (int u = 0; u < 128; ++u) {
        float p = __expf(fmaf(qs, klds[u], -m));
        S += p;
#pragma unroll
        for (int c = 0; c < 15; ++c)
            acc[c] = fmaf(p, vlds[c][u], acc[c]);
    }
    float scale = gptr[0] / S;
#pragma unroll
    for (int c = 0; c < 15; ++c) {
        size_t idx = (((size_t)bb * 15 + c) * 256 + hh) * 128 + w;
        hout[idx] = fmaf(scale, acc[c], hin[idx]);
    }
}

// out[m, 0..127] = A[m, 0..127] @ Bm(128x128) (+ bias). grid = M/16, block = 256.
__global__ __launch_bounds__(256) void gemm128_k(const float* __restrict__ A,
                                                 const float* __restrict__ Bm,
                                                 const float* __restrict__ bias,
                                                 float* __restrict__ out) {
    __shared__ float Al[16][128];
    int m0 = blockIdx.x * 16;
    int tx = threadIdx.x & 127, ty = threadIdx.x >> 7;
#pragma unroll
    for (int j = 0; j < 8; ++j) {
        int e = threadIdx.x + 256 * j;
        Al[e >> 7][e & 127] = A[(size_t)m0 * 128 + e];
    }
    __syncthreads();
    float acc[8];
#pragma unroll
    for (int r = 0; r < 8; ++r) acc[r] = 0.f;
#pragma unroll 4
    for (int kk = 0; kk < 128; ++kk) {
        float bv = Bm[kk * 128 + tx];
#pragma unroll
        for (int r = 0; r < 8; ++r)
            acc[r] = fmaf(Al[2 * r + ty][kk], bv, acc[r]);
    }
    float bb = bias ? bias[tx] : 0.f;
#pragma unroll
    for (int r = 0; r < 8; ++r)
        out[(size_t)(m0 + 2 * r + ty) * 128 + tx] = acc[r] + bb;
}

// out[m, 0..4095] = A[m, 0..127] @ Bm(128x4096) + bias. 16 rows x 512 cols per block.
__global__ __launch_bounds__(256) void gemmP2_k(const float* __restrict__ A,
                                                const float* __restrict__ Bm,
                                                const float* __restrict__ bias,
                                                float* __restrict__ out) {
    __shared__ float Al[16][128];
    int rb = blockIdx.x >> 3, cblk = blockIdx.x & 7;
    int m0 = rb * 16, cb = cblk * 512;
    int tx = threadIdx.x & 127, ty = threadIdx.x >> 7;
#pragma unroll
    for (int j = 0; j < 8; ++j) {
        int e = threadIdx.x + 256 * j;
        Al[e >> 7][e & 127] = A[(size_t)m0 * 128 + e];
    }
    __syncthreads();
    float acc[8][4];
#pragma unroll
    for (int r = 0; r < 8; ++r)
#pragma unroll
        for (int j = 0; j < 4; ++j) acc[r][j] = 0.f;
#pragma unroll 2
    for (int kk = 0; kk < 128; ++kk) {
        const float* brow = Bm + (size_t)kk * 4096 + cb + tx;
        float b0 = brow[0], b1 = brow[128], b2 = brow[256], b3 = brow[384];
#pragma unroll
        for (int r = 0; r < 8; ++r) {
            float a = Al[2 * r + ty][kk];
            acc[r][0] = fmaf(a, b0, acc[r][0]);
            acc[r][1] = fmaf(a, b1, acc[r][1]);
            acc[r][2] = fmaf(a, b2, acc[r][2]);
            acc[r][3] = fmaf(a, b3, acc[r][3]);
        }
    }
#pragma unroll
    for (int r = 0; r < 8; ++r) {
        size_t row = m0 + 2 * r + ty;
#pragma unroll
        for (int j = 0; j < 4; ++j) {
            int col = cb + tx + 128 * j;
            out[row * 4096 + col] = acc[r][j] + bias[col];
        }
    }
}

extern "C" void kernel_launch(void* const* d_in, const int* in_sizes, int n_in,
                              void* d_out, int out_size, void* d_ws, size_t ws_size,
                              hipStream_t stream) {
    const float* x    = (const float*)d_in[0];
    const float* Wemb = (const float*)d_in[1];
    const float* bemb = (const float*)d_in[2];
    const float* Wq   = (const float*)d_in[3];
    const float* bq   = (const float*)d_in[4];
    const float* Wk   = (const float*)d_in[5];
    const float* bk   = (const float*)d_in[6];
    const float* Wv   = (const float*)d_in[7];
    const float* bv   = (const float*)d_in[8];
    const float* gam  = (const float*)d_in[9];
    const float* Wmlp = (const float*)d_in[10];
    const float* Wp1  = (const float*)d_in[11];
    const float* bp1  = (const float*)d_in[12];
    const float* Wp2  = (const float*)d_in[13];
    const float* bp2  = (const float*)d_in[14];

    float* out = (float*)d_out;
    float* xe  = out + XE_OFF;
    float* xh  = out + XH_OFF;
    float* xp  = out + XP_OFF;
    float* xhp = out + XHP_OFF;

    // scratch lives in the (not-yet-final) x_h_p region; z in ws (3.93 MB)
    float* scr  = xhp;
    float* cosb = scr + SCR_COS;
    float* sinb = scr + SCR_SIN;
    float* qb   = scr + SCR_Q;
    float* kb   = scr + SCR_K;
    float* vb   = scr + SCR_V;
    float* ha   = scr + SCR_HA;
    float* hb   = scr + SCR_HB;
    float* z    = (float*)d_ws;

    rope_tab_k<<<32, 256, 0, stream>>>(cosb, sinb);
    embed_k<<<480, 256, 0, stream>>>(x, Wemb, bemb, xe);

    const float* hin = xe;
    float* houts[3] = {ha, hb, ha};
    for (int i = 0; i < 3; ++i) {
        qkv_k<<<512, 128, 0, stream>>>(hin, Wq + i * 15, bq + i, Wk + i * 15, bk + i,
                                       Wv + i * 225, bv + i * 15, cosb, sinb, qb, kb, vb);
        attn_k<<<512, 128, 0, stream>>>(hin, qb, kb, vb, gam + i, houts[i]);
        hin = houts[i];
    }

    gemm128_k<<<480, 256, 0, stream>>>(hin, Wmlp, nullptr, xh);   // x_h
    gemm128_k<<<480, 256, 0, stream>>>(xe, Wp1, bp1, z);          // z1
    gemmP2_k<<<3840, 256, 0, stream>>>(z, Wp2, bp2, xp);          // x_p
    gemm128_k<<<480, 256, 0, stream>>>(xh, Wp1, bp1, z);          // z2
    gemmP2_k<<<3840, 256, 0, stream>>>(z, Wp2, bp2, xhp);         // x_h_p (overwrites scratch)
}

// Round 2
// 1341.751 us; speedup vs baseline: 1.0115x; 1.0115x over previous
//
#include <hip/hip_runtime.h>
#include <math.h>

// Shapes: b=2, T=15, Hn=256, D=128, P=64, PPP=4096, REC=3
// d_out layout (f32): x_e[983040] | x_h[983040] | x_p[31457280] | x_h_p[31457280]
#define XE_OFF   0
#define XH_OFF   983040
#define XP_OFF   1966080
#define XHP_OFF  33423360

// scratch inside x_h_p region (written last, so free until the final kernel)
#define SCR_COS  0        // 8192
#define SCR_SIN  8192     // 8192
#define SCR_Q    16384    // 65536
#define SCR_K    81920    // 65536
#define SCR_V    147456   // 983040
#define SCR_HA   1130496  // 983040
#define SCR_HB   2113536  // 983040  (ends at 3096576)
#define SCR_PART 4194304  // 4 x 983040 = 3932160 floats (ends at 8126464 < 31457280)

__global__ __launch_bounds__(256) void rope_tab_k(float* __restrict__ cosb,
                                                  float* __restrict__ sinb) {
    int i = blockIdx.x * 256 + threadIdx.x;   // 8192 entries = 256 pos x 32 j
    int n = i >> 5, j = i & 31;
    float inv = expf(-(float)j * 0.28782313662425573f);  // 10000^(-2j/64)
    float ang = (float)n * inv;
    cosb[i] = cosf(ang);
    sinb[i] = sinf(ang);
}

// Patch-embed GEMM, split-K x4. grid = 480 m-tiles * 4 k-chunks.
// Per block: 16 rows x 128 cols, K-chunk = 1024 (16 kc of 64).
// Thread: tx=tid&31 -> cols 4*tx..+3 (float4 B); ry=tid>>5 -> rows ry, ry+8.
__global__ __launch_bounds__(256) void embed_part_k(const float* __restrict__ x,
                                                    const float* __restrict__ Wemb,
                                                    float* __restrict__ part) {
    __shared__ float A[16][64];
    int bid = blockIdx.x;
    int mt = bid >> 2, ck = bid & 3;
    int m0 = mt * 16;
    int bt = m0 >> 8, n0 = m0 & 255;       // 16 rows never cross (b,t): 256%16==0
    const float* xbase = x + (size_t)bt * 1048576;
    int tid = threadIdx.x;
    int tx = tid & 31, ry = tid >> 5;
    float4 acc0 = {0.f, 0.f, 0.f, 0.f};
    float4 acc1 = {0.f, 0.f, 0.f, 0.f};

    for (int kci = 0; kci < 16; ++kci) {
        int kc = ck * 16 + kci;            // kc == py
        __syncthreads();
#pragma unroll
        for (int j = 0; j < 4; ++j) {
            int e = j * 256 + tid;
            int r = e >> 6, kk = e & 63;
            int n = n0 + r;
            A[r][kk] = xbase[((n >> 4) * 64 + kc) * 1024 + (n & 15) * 64 + kk];
        }
        __syncthreads();
        const float4* Bp = (const float4*)Wemb + (size_t)(kc * 64) * 32;
#pragma unroll 8
        for (int kk = 0; kk < 64; ++kk) {
            float a0 = A[ry][kk];          // 2-way broadcast ds_read (free)
            float a1 = A[ry + 8][kk];
            float4 bv = Bp[kk * 32 + tx];  // global_load_dwordx4, L2-resident
            acc0.x = fmaf(a0, bv.x, acc0.x); acc0.y = fmaf(a0, bv.y, acc0.y);
            acc0.z = fmaf(a0, bv.z, acc0.z); acc0.w = fmaf(a0, bv.w, acc0.w);
            acc1.x = fmaf(a1, bv.x, acc1.x); acc1.y = fmaf(a1, bv.y, acc1.y);
            acc1.z = fmaf(a1, bv.z, acc1.z); acc1.w = fmaf(a1, bv.w, acc1.w);
        }
    }
    float* p = part + (size_t)ck * 983040;
    ((float4*)(p + (size_t)(m0 + ry) * 128))[tx] = acc0;
    ((float4*)(p + (size_t)(m0 + ry + 8) * 128))[tx] = acc1;
}

// xe = part0+part1+part2+part3 + bias. grid = 960, block = 256, float4 per thread.
__global__ __launch_bounds__(256) void embed_reduce_k(const float* __restrict__ part,
                                                      const float* __restrict__ bemb,
                                                      float* __restrict__ xe) {
    int i = blockIdx.x * 256 + threadIdx.x;    // float4 index, 245760 total
    const float4* p = (const float4*)part;
    float4 a = p[i], b = p[245760 + i], c = p[491520 + i], d = p[737280 + i];
    float4 bb = ((const float4*)bemb)[i & 31];
    float4 r;
    r.x = a.x + b.x + c.x + d.x + bb.x;
    r.y = a.y + b.y + c.y + d.y + bb.y;
    r.z = a.z + b.z + c.z + d.z + bb.z;
    r.w = a.w + b.w + c.w + d.w + bb.w;
    ((float4*)xe)[i] = r;
}

// q/k (+RoPE) and v projections. grid = b*256*4 (bn, part), block = 128 (=d).
// part 0: q,k ; parts 1..3: v channels 5 each.
__global__ __launch_bounds__(128) void qkv_k(const float* __restrict__ h,
                                             const float* __restrict__ Wq, const float* __restrict__ bq,
                                             const float* __restrict__ Wk, const float* __restrict__ bk,
                                             const float* __restrict__ Wv, const float* __restrict__ bv,
                                             const float* __restrict__ cosb, const float* __restrict__ sinb,
                                             float* __restrict__ q, float* __restrict__ k,
                                             float* __restrict__ v) {
    int bid = blockIdx.x;
    int bn = bid >> 2, part = bid & 3;
    int b = bn >> 8, n = bn & 255;
    int d = threadIdx.x;
    float hv[15];
#pragma unroll
    for (int t = 0; t < 15; ++t)
        hv[t] = h[(((size_t)b * 15 + t) * 256 + n) * 128 + d];

    if (part == 0) {
        float qp = bq[0], kp = bk[0];
#pragma unroll
        for (int t = 0; t < 15; ++t) {
            qp = fmaf(hv[t], Wq[t], qp);
            kp = fmaf(hv[t], Wk[t], kp);
        }
        float qpart = __shfl_xor(qp, 1);
        float kpart = __shfl_xor(kp, 1);
        float qo = qp, ko = kp;
        if (d < 64) {
            int j = d >> 1;
            float c = cosb[n * 32 + j], s = sinb[n * 32 + j];
            if (d & 1) { qo = fmaf(qp, c,  qpart * s); ko = fmaf(kp, c,  kpart * s); }
            else       { qo = fmaf(qp, c, -qpart * s); ko = fmaf(kp, c, -kpart * s); }
        }
        q[((size_t)b * 256 + n) * 128 + d] = qo;
        k[((size_t)b * 256 + n) * 128 + d] = ko;
    } else {
        int c0 = (part - 1) * 5;
#pragma unroll
        for (int j = 0; j < 5; ++j) {
            int c = c0 + j;
            float a = bv[c];
#pragma unroll
            for (int t = 0; t < 15; ++t) a = fmaf(hv[t], Wv[c * 15 + t], a);
            v[(((size_t)b * 15 + c) * 256 + n) * 128 + d] = a;
        }
    }
}

// Criss-cross attention + residual. grid = b*256 (b,h), block = 512 (4 cgroups x 128 w).
__global__ __launch_bounds__(512) void attn_k(const float* __restrict__ hin,
                                              const float* __restrict__ q,
                                              const float* __restrict__ k,
                                              const float* __restrict__ v,
                                              const float* __restrict__ gptr,
                                              float* __restrict__ hout) {
    __shared__ float klds[128];
    __shared__ float vlds[15][128];
    int bb = blockIdx.x >> 8, hh = blockIdx.x & 255;
    int tid = threadIdx.x;
    int w = tid & 127, cg = tid >> 7;
    const float* kb = k + (size_t)bb * 32768;
    const float* vb = v + (size_t)bb * 491520;
    for (int e = tid; e < 1920; e += 512) {
        int c = e >> 7, u = e & 127;
        vlds[c][u] = vb[(c * 256 + hh) * 128 + u];
    }
    if (tid < 128) klds[tid] = kb[hh * 128 + tid];
    float qs = q[((size_t)bb * 256 + hh) * 128 + w];
    __syncthreads();

    // pass 1: max over 384 logits
    float m = -3.4e38f;
    for (int g = 0; g < 256; ++g) {
        float lg = qs * kb[g * 128 + w];
        if (g != hh) m = fmaxf(m, lg);
    }
#pragma unroll 8
    for (int u = 0; u < 128; ++u)
        m = fmaxf(m, qs * klds[u]);

    // pass 2: exp + weighted accumulate (each cgroup owns 4 (or 3) channels)
    int c0 = cg * 4;
    int nc = (cg == 3) ? 3 : 4;
    float S = 0.f;
    float acc[4] = {0.f, 0.f, 0.f, 0.f};
    for (int g = 0; g < 256; ++g) {
        if (g == hh) continue;
        float p = __expf(fmaf(qs, kb[g * 128 + w], -m));
        S += p;
        const float* vg = vb + (size_t)(c0 * 256 + g) * 128 + w;
#pragma unroll
        for (int j = 0; j < 4; ++j)
            if (j < nc) acc[j] = fmaf(p, vg[(size_t)j * 32768], acc[j]);
    }
#pragma unroll 4
    for (int u = 0; u < 128; ++u) {
        float p = __expf(fmaf(qs, klds[u], -m));
        S += p;
#pragma unroll
        for (int j = 0; j < 4; ++j)
            if (j < nc) acc[j] = fmaf(p, vlds[c0 + j][u], acc[j]);
    }
    float scale = gptr[0] / S;
#pragma unroll
    for (int j = 0; j < 4; ++j) {
        if (j < nc) {
            size_t idx = (((size_t)bb * 15 + c0 + j) * 256 + hh) * 128 + w;
            hout[idx] = fmaf(scale, acc[j], hin[idx]);
        }
    }
}

// out[m,0..127] = A[m,:] @ Bm(128x128) (+bias). grid = M/8 = 960, block = 256.
// Thread: tx=tid&31 -> cols 4tx (float4); ry=tid>>5 -> row ry.
__global__ __launch_bounds__(256) void gemm128_k(const float* __restrict__ A,
                                                 const float* __restrict__ Bm,
                                                 const float* __restrict__ bias,
                                                 float* __restrict__ out) {
    __shared__ float Al[1024];
    int m0 = blockIdx.x * 8;
    int tid = threadIdx.x;
    int tx = tid & 31, ry = tid >> 5;
    ((float4*)Al)[tid] = ((const float4*)(A + (size_t)m0 * 128))[tid];
    __syncthreads();
    float4 acc = {0.f, 0.f, 0.f, 0.f};
    const float4* Bp = (const float4*)Bm;
#pragma unroll 8
    for (int kk = 0; kk < 128; ++kk) {
        float a = Al[ry * 128 + kk];       // broadcast
        float4 bv = Bp[kk * 32 + tx];
        acc.x = fmaf(a, bv.x, acc.x); acc.y = fmaf(a, bv.y, acc.y);
        acc.z = fmaf(a, bv.z, acc.z); acc.w = fmaf(a, bv.w, acc.w);
    }
    if (bias) {
        float4 bb = ((const float4*)bias)[tx];
        acc.x += bb.x; acc.y += bb.y; acc.z += bb.z; acc.w += bb.w;
    }
    ((float4*)(out + (size_t)(m0 + ry) * 128))[tx] = acc;
}

// out[m,0..4095] = A[m,:] @ Bm(128x4096) + bias. 16 rows x 512 cols per block.
// Thread: tx=tid&63 -> 8 cols at cb+8tx (2 float4); rg=tid>>6 -> rows rg*4..+3.
__global__ __launch_bounds__(256) void gemmP2_k(const float* __restrict__ A,
                                                const float* __restrict__ Bm,
                                                const float* __restrict__ bias,
                                                float* __restrict__ out) {
    __shared__ float Al[2048];
    int rb = blockIdx.x >> 3, cblk = blockIdx.x & 7;
    int m0 = rb * 16, cb = cblk * 512;
    int tid = threadIdx.x;
    int tx = tid & 63, rg = tid >> 6;
    ((float4*)Al)[tid]       = ((const float4*)(A + (size_t)m0 * 128))[tid];
    ((float4*)Al)[tid + 256] = ((const float4*)(A + (size_t)m0 * 128))[tid + 256];
    __syncthreads();
    float4 acc[4][2];
#pragma unroll
    for (int r = 0; r < 4; ++r) {
        acc[r][0] = make_float4(0.f, 0.f, 0.f, 0.f);
        acc[r][1] = make_float4(0.f, 0.f, 0.f, 0.f);
    }
#pragma unroll 2
    for (int kk = 0; kk < 128; ++kk) {
        const float4* Bp = (const float4*)(Bm + (size_t)kk * 4096 + cb);
        float4 b0 = Bp[2 * tx], b1 = Bp[2 * tx + 1];
#pragma unroll
        for (int r = 0; r < 4; ++r) {
            float a = Al[(rg * 4 + r) * 128 + kk];   // broadcast
            acc[r][0].x = fmaf(a, b0.x, acc[r][0].x); acc[r][0].y = fmaf(a, b0.y, acc[r][0].y);
            acc[r][0].z = fmaf(a, b0.z, acc[r][0].z); acc[r][0].w = fmaf(a, b0.w, acc[r][0].w);
            acc[r][1].x = fmaf(a, b1.x, acc[r][1].x); acc[r][1].y = fmaf(a, b1.y, acc[r][1].y);
            acc[r][1].z = fmaf(a, b1.z, acc[r][1].z); acc[r][1].w = fmaf(a, b1.w, acc[r][1].w);
        }
    }
    float4 bb0 = ((const float4*)(bias + cb))[2 * tx];
    float4 bb1 = ((const float4*)(bias + cb))[2 * tx + 1];
#pragma unroll
    for (int r = 0; r < 4; ++r) {
        size_t row = m0 + rg * 4 + r;
        float4 o0, o1;
        o0.x = acc[r][0].x + bb0.x; o0.y = acc[r][0].y + bb0.y;
        o0.z = acc[r][0].z + bb0.z; o0.w = acc[r][0].w + bb0.w;
        o1.x = acc[r][1].x + bb1.x; o1.y = acc[r][1].y + bb1.y;
        o1.z = acc[r][1].z + bb1.z; o1.w = acc[r][1].w + bb1.w;
        ((float4*)(out + row * 4096 + cb))[2 * tx] = o0;
        ((float4*)(out + row * 4096 + cb))[2 * tx + 1] = o1;
    }
}

extern "C" void kernel_launch(void* const* d_in, const int* in_sizes, int n_in,
                              void* d_out, int out_size, void* d_ws, size_t ws_size,
                              hipStream_t stream) {
    const float* x    = (const float*)d_in[0];
    const float* Wemb = (const float*)d_in[1];
    const float* bemb = (const float*)d_in[2];
    const float* Wq   = (const float*)d_in[3];
    const float* bq   = (const float*)d_in[4];
    const float* Wk   = (const float*)d_in[5];
    const float* bk   = (const float*)d_in[6];
    const float* Wv   = (const float*)d_in[7];
    const float* bv   = (const float*)d_in[8];
    const float* gam  = (const float*)d_in[9];
    const float* Wmlp = (const float*)d_in[10];
    const float* Wp1  = (const float*)d_in[11];
    const float* bp1  = (const float*)d_in[12];
    const float* Wp2  = (const float*)d_in[13];
    const float* bp2  = (const float*)d_in[14];

    float* out = (float*)d_out;
    float* xe  = out + XE_OFF;
    float* xh  = out + XH_OFF;
    float* xp  = out + XP_OFF;
    float* xhp = out + XHP_OFF;

    float* scr  = xhp;
    float* cosb = scr + SCR_COS;
    float* sinb = scr + SCR_SIN;
    float* qb   = scr + SCR_Q;
    float* kb   = scr + SCR_K;
    float* vb   = scr + SCR_V;
    float* ha   = scr + SCR_HA;
    float* hb   = scr + SCR_HB;
    float* prt  = scr + SCR_PART;
    float* z    = (float*)d_ws;

    rope_tab_k<<<32, 256, 0, stream>>>(cosb, sinb);
    embed_part_k<<<1920, 256, 0, stream>>>(x, Wemb, prt);
    embed_reduce_k<<<960, 256, 0, stream>>>(prt, bemb, xe);

    const float* hin = xe;
    float* houts[3] = {ha, hb, ha};
    for (int i = 0; i < 3; ++i) {
        qkv_k<<<2048, 128, 0, stream>>>(hin, Wq + i * 15, bq + i, Wk + i * 15, bk + i,
                                        Wv + i * 225, bv + i * 15, cosb, sinb, qb, kb, vb);
        attn_k<<<512, 512, 0, stream>>>(hin, qb, kb, vb, gam + i, houts[i]);
        hin = houts[i];
    }

    gemm128_k<<<960, 256, 0, stream>>>(hin, Wmlp, nullptr, xh);   // x_h
    gemm128_k<<<960, 256, 0, stream>>>(xe, Wp1, bp1, z);          // z1
    gemmP2_k<<<3840, 256, 0, stream>>>(z, Wp2, bp2, xp);          // x_p
    gemm128_k<<<960, 256, 0, stream>>>(xh, Wp1, bp1, z);          // z2
    gemmP2_k<<<3840, 256, 0, stream>>>(z, Wp2, bp2, xhp);         // x_h_p
}

// Round 3
// 903.236 us; speedup vs baseline: 1.5026x; 1.4855x over previous
//
#include <hip/hip_runtime.h>
#include <math.h>

typedef __attribute__((ext_vector_type(8))) short bf16x8;
typedef __attribute__((ext_vector_type(8))) unsigned short u16x8;
typedef __attribute__((ext_vector_type(4))) float f32x4;
typedef unsigned short u16;

// Shapes: b=2, T=15, Hn=256, D=128, P=64, PPP=4096, REC=3
// d_out layout (f32): x_e[983040] | x_h[983040] | x_p[31457280] | x_h_p[31457280]
#define XE_OFF   0
#define XH_OFF   983040
#define XP_OFF   1966080
#define XHP_OFF  33423360

// scratch (float offsets) inside x_h_p region — all dead before the final gemm
#define SCR_COS   0         // 8192
#define SCR_SIN   8192      // 8192
#define SCR_Q     16384     // 65536
#define SCR_K     81920     // 65536
#define SCR_V     147456    // 983040
#define SCR_HA    1130496   // 983040
#define SCR_HB    2113536   // 983040 (ends 3096576)
#define SCR_PART  4194304   // 8 x 983040 = 7864320 (ends 12058624)
#define SCR_WEMBT 12582912  // 524288 u16 = 262144 f (ends 12845056)
#define SCR_WP1T  12845056  // 16384 u16 (ends 12853248)
#define SCR_WMLPT 12853248  // 16384 u16 (ends 12861440)
// d_ws layout (bytes): [0..1966080) z_bf16 ; [2097152..3145728) Wp2t_bf16

__device__ __forceinline__ u16 f2bf(float f) {
    unsigned u = __float_as_uint(f);
    return (u16)((u + 0x7fffu + ((u >> 16) & 1)) >> 16);
}

union U8 { u16 h[8]; bf16x8 v; u16x8 u; };

__global__ __launch_bounds__(256) void rope_tab_k(float* __restrict__ cosb,
                                                  float* __restrict__ sinb) {
    int i = blockIdx.x * 256 + threadIdx.x;   // 8192 = 256 pos x 32 j
    int n = i >> 5, j = i & 31;
    float inv = expf(-(float)j * 0.28782313662425573f);  // 10000^(-2j/64)
    float ang = (float)n * inv;
    cosb[i] = cosf(ang);
    sinb[i] = sinf(ang);
}

// transpose + f32->bf16: out[N][K] = cvt(in[K][N]). grid = (N/32, K/32), block 256.
__global__ __launch_bounds__(256) void tcvt_k(const float* __restrict__ in,
                                              u16* __restrict__ out, int K, int N) {
    __shared__ float tl[32][33];
    int n0 = blockIdx.x * 32, k0 = blockIdx.y * 32;
    int tx = threadIdx.x & 31, ty = threadIdx.x >> 5;
#pragma unroll
    for (int r = 0; r < 4; ++r)
        tl[ty + r * 8][tx] = in[(size_t)(k0 + ty + r * 8) * N + n0 + tx];
    __syncthreads();
#pragma unroll
    for (int r = 0; r < 4; ++r)
        out[(size_t)(n0 + ty + r * 8) * K + k0 + tx] = f2bf(tl[tx][ty + r * 8]);
}

// ---------------- embed: MFMA bf16, split-K x8 ----------------
// grid (8 kchunks, 120 mtiles), block 256 (4 waves, 2x2).
// Per block: out tile 64x128, K-chunk 512 (8 steps of BK=64).
__global__ __launch_bounds__(256) void embed_mfma_k(const float* __restrict__ x,
                                                    const u16* __restrict__ Wembt,
                                                    float* __restrict__ part) {
    __shared__ char Al[64 * 128];    // [row][k] bf16, swizzled
    __shared__ char Bl[128 * 128];   // [n][k] bf16, swizzled
    int ck = blockIdx.x, mt = blockIdx.y;
    int m0 = mt * 64;
    int bt = m0 >> 8;
    int n0r = m0 & 255;
    const float* xb = x + (size_t)bt * 1048576;
    int tid = threadIdx.x;
    int ln = tid & 63, wv = tid >> 6;
    int wm = wv >> 1, wn = wv & 1;

    f32x4 zero4 = {0.f, 0.f, 0.f, 0.f};
    f32x4 acc[2][4];
#pragma unroll
    for (int mi = 0; mi < 2; ++mi)
#pragma unroll
        for (int ni = 0; ni < 4; ++ni) acc[mi][ni] = zero4;

    // A staging coords: row ar (0..63), 16 floats at kseg = aseg*16
    int ar = tid & 63, aseg = tid >> 6;
    int an = n0r + ar;
    const float* arow = xb + ((size_t)(an >> 4) * 64) * 1024 + (an & 15) * 64;

    for (int bk = 0; bk < 8; ++bk) {
        int kbase = ck * 512 + bk * 64;   // global k; py = kbase>>6, px = 0..63
        __syncthreads();
        // stage A: 64 rows x 64 k (f32 -> bf16)
        {
            const float* src = arow + (size_t)(kbase >> 6) * 1024 + aseg * 16;
            float4 f0 = ((const float4*)src)[0];
            float4 f1 = ((const float4*)src)[1];
            float4 f2 = ((const float4*)src)[2];
            float4 f3 = ((const float4*)src)[3];
            U8 u0, u1;
            u0.h[0] = f2bf(f0.x); u0.h[1] = f2bf(f0.y); u0.h[2] = f2bf(f0.z); u0.h[3] = f2bf(f0.w);
            u0.h[4] = f2bf(f1.x); u0.h[5] = f2bf(f1.y); u0.h[6] = f2bf(f1.z); u0.h[7] = f2bf(f1.w);
            u1.h[0] = f2bf(f2.x); u1.h[1] = f2bf(f2.y); u1.h[2] = f2bf(f2.z); u1.h[3] = f2bf(f2.w);
            u1.h[4] = f2bf(f3.x); u1.h[5] = f2bf(f3.y); u1.h[6] = f2bf(f3.z); u1.h[7] = f2bf(f3.w);
            int sw = (ar & 7) << 4;
            *(bf16x8*)(Al + ar * 128 + ((aseg * 32) ^ sw))      = u0.v;
            *(bf16x8*)(Al + ar * 128 + ((aseg * 32 + 16) ^ sw)) = u1.v;
        }
        // stage B: 128 n x 64 k bf16 from Wembt[n][kbase..]
#pragma unroll
        for (int j = 0; j < 4; ++j) {
            int c = tid + 256 * j;
            int n = c >> 3, k0 = (c & 7) * 8;
            U8 u;
            u.u = *(const u16x8*)(Wembt + (size_t)n * 4096 + kbase + k0);
            *(bf16x8*)(Bl + n * 128 + ((k0 * 2) ^ ((n & 7) << 4))) = u.v;
        }
        __syncthreads();
        // compute: 2 k-steps of 32, 2x4 fragments
#pragma unroll
        for (int ks = 0; ks < 2; ++ks) {
            int k2 = (ks * 32 + (ln >> 4) * 8) * 2;
            bf16x8 a[2], b[4];
#pragma unroll
            for (int mi = 0; mi < 2; ++mi) {
                int row = wm * 32 + mi * 16 + (ln & 15);
                a[mi] = *(const bf16x8*)(Al + row * 128 + (k2 ^ ((row & 7) << 4)));
            }
#pragma unroll
            for (int ni = 0; ni < 4; ++ni) {
                int n = wn * 64 + ni * 16 + (ln & 15);
                b[ni] = *(const bf16x8*)(Bl + n * 128 + (k2 ^ ((n & 7) << 4)));
            }
#pragma unroll
            for (int mi = 0; mi < 2; ++mi)
#pragma unroll
                for (int ni = 0; ni < 4; ++ni)
                    acc[mi][ni] = __builtin_amdgcn_mfma_f32_16x16x32_bf16(a[mi], b[ni], acc[mi][ni], 0, 0, 0);
        }
    }
    float* p = part + (size_t)ck * 983040;
#pragma unroll
    for (int mi = 0; mi < 2; ++mi)
#pragma unroll
        for (int ni = 0; ni < 4; ++ni)
#pragma unroll
            for (int r = 0; r < 4; ++r) {
                int row = m0 + wm * 32 + mi * 16 + (ln >> 4) * 4 + r;
                int col = wn * 64 + ni * 16 + (ln & 15);
                p[(size_t)row * 128 + col] = acc[mi][ni][r];
            }
}

// xe = sum of 8 parts + bias. grid 960, block 256, float4.
__global__ __launch_bounds__(256) void embed_reduce_k(const float* __restrict__ part,
                                                      const float* __restrict__ bemb,
                                                      float* __restrict__ xe) {
    int i = blockIdx.x * 256 + threadIdx.x;   // float4 idx, 245760 total
    const float4* p = (const float4*)part;
    float4 s = p[i];
#pragma unroll
    for (int j = 1; j < 8; ++j) {
        float4 a = p[(size_t)j * 245760 + i];
        s.x += a.x; s.y += a.y; s.z += a.z; s.w += a.w;
    }
    float4 bb = ((const float4*)bemb)[i & 31];
    s.x += bb.x; s.y += bb.y; s.z += bb.z; s.w += bb.w;
    ((float4*)xe)[i] = s;
}

// ---------------- generic K=128 MFMA GEMM: out[M][N] = A[M][128] @ Bt[N][128]^T (+bias) ----
// grid (N/128, M/64), block 256. ABF: A is bf16; OBF: out bf16; HASB: add bias.
template<int ABF, int OBF, int HASB>
__global__ __launch_bounds__(256) void gemm_bt_k(const void* __restrict__ Ap,
                                                 const u16* __restrict__ Bt,
                                                 const float* __restrict__ bias,
                                                 void* __restrict__ outp, int N) {
    __shared__ char Al[64 * 256];    // [64 rows][128 k] bf16 swizzled
    __shared__ char Bl[128 * 256];   // [128 n][128 k] bf16 swizzled
    int n0 = blockIdx.x * 128, m0 = blockIdx.y * 64;
    int tid = threadIdx.x;
    int ln = tid & 63, wv = tid >> 6;
    int wm = wv >> 1, wn = wv & 1;

    // stage A: thread -> row = tid>>2, kseg = (tid&3)*32
    {
        int row = tid >> 2, kseg = (tid & 3) * 32;
        int sw = (row & 7) << 4;
        if (ABF) {
            const u16* src = (const u16*)Ap + (size_t)(m0 + row) * 128 + kseg;
#pragma unroll
            for (int j = 0; j < 4; ++j) {
                U8 u; u.u = *(const u16x8*)(src + j * 8);
                *(bf16x8*)(Al + row * 256 + (((kseg + j * 8) * 2) ^ sw)) = u.v;
            }
        } else {
            const float* src = (const float*)Ap + (size_t)(m0 + row) * 128 + kseg;
#pragma unroll
            for (int j = 0; j < 4; ++j) {
                float4 f0 = ((const float4*)src)[2 * j];
                float4 f1 = ((const float4*)src)[2 * j + 1];
                U8 u;
                u.h[0] = f2bf(f0.x); u.h[1] = f2bf(f0.y); u.h[2] = f2bf(f0.z); u.h[3] = f2bf(f0.w);
                u.h[4] = f2bf(f1.x); u.h[5] = f2bf(f1.y); u.h[6] = f2bf(f1.z); u.h[7] = f2bf(f1.w);
                *(bf16x8*)(Al + row * 256 + (((kseg + j * 8) * 2) ^ sw)) = u.v;
            }
        }
    }
    // stage B: thread -> n = tid>>1, kseg = (tid&1)*64 (8 chunks of 8)
    {
        int n = tid >> 1, kseg = (tid & 1) * 64;
        int sw = (n & 7) << 4;
        const u16* src = Bt + (size_t)(n0 + n) * 128 + kseg;
#pragma unroll
        for (int j = 0; j < 8; ++j) {
            U8 u; u.u = *(const u16x8*)(src + j * 8);
            *(bf16x8*)(Bl + n * 256 + (((kseg + j * 8) * 2) ^ sw)) = u.v;
        }
    }
    __syncthreads();

    f32x4 zero4 = {0.f, 0.f, 0.f, 0.f};
    f32x4 acc[2][4];
#pragma unroll
    for (int mi = 0; mi < 2; ++mi)
#pragma unroll
        for (int ni = 0; ni < 4; ++ni) acc[mi][ni] = zero4;

#pragma unroll
    for (int ks = 0; ks < 4; ++ks) {
        int k2 = (ks * 32 + (ln >> 4) * 8) * 2;
        bf16x8 a[2], b[4];
#pragma unroll
        for (int mi = 0; mi < 2; ++mi) {
            int row = wm * 32 + mi * 16 + (ln & 15);
            a[mi] = *(const bf16x8*)(Al + row * 256 + (k2 ^ ((row & 7) << 4)));
        }
#pragma unroll
        for (int ni = 0; ni < 4; ++ni) {
            int n = wn * 64 + ni * 16 + (ln & 15);
            b[ni] = *(const bf16x8*)(Bl + n * 256 + (k2 ^ ((n & 7) << 4)));
        }
#pragma unroll
        for (int mi = 0; mi < 2; ++mi)
#pragma unroll
            for (int ni = 0; ni < 4; ++ni)
                acc[mi][ni] = __builtin_amdgcn_mfma_f32_16x16x32_bf16(a[mi], b[ni], acc[mi][ni], 0, 0, 0);
    }

#pragma unroll
    for (int mi = 0; mi < 2; ++mi)
#pragma unroll
        for (int ni = 0; ni < 4; ++ni)
#pragma unroll
            for (int r = 0; r < 4; ++r) {
                int row = m0 + wm * 32 + mi * 16 + (ln >> 4) * 4 + r;
                int col = n0 + wn * 64 + ni * 16 + (ln & 15);
                float v = acc[mi][ni][r];
                if (HASB) v += bias[col];
                if (OBF) ((u16*)outp)[(size_t)row * N + col] = f2bf(v);
                else     ((float*)outp)[(size_t)row * N + col] = v;
            }
}

// ---------------- qkv + attention (f32, unchanged from round 2) ----------------
__global__ __launch_bounds__(128) void qkv_k(const float* __restrict__ h,
                                             const float* __restrict__ Wq, const float* __restrict__ bq,
                                             const float* __restrict__ Wk, const float* __restrict__ bk,
                                             const float* __restrict__ Wv, const float* __restrict__ bv,
                                             const float* __restrict__ cosb, const float* __restrict__ sinb,
                                             float* __restrict__ q, float* __restrict__ k,
                                             float* __restrict__ v) {
    int bid = blockIdx.x;
    int bn = bid >> 2, part = bid & 3;
    int b = bn >> 8, n = bn & 255;
    int d = threadIdx.x;
    float hv[15];
#pragma unroll
    for (int t = 0; t < 15; ++t)
        hv[t] = h[(((size_t)b * 15 + t) * 256 + n) * 128 + d];

    if (part == 0) {
        float qp = bq[0], kp = bk[0];
#pragma unroll
        for (int t = 0; t < 15; ++t) {
            qp = fmaf(hv[t], Wq[t], qp);
            kp = fmaf(hv[t], Wk[t], kp);
        }
        float qpart = __shfl_xor(qp, 1);
        float kpart = __shfl_xor(kp, 1);
        float qo = qp, ko = kp;
        if (d < 64) {
            int j = d >> 1;
            float c = cosb[n * 32 + j], s = sinb[n * 32 + j];
            if (d & 1) { qo = fmaf(qp, c,  qpart * s); ko = fmaf(kp, c,  kpart * s); }
            else       { qo = fmaf(qp, c, -qpart * s); ko = fmaf(kp, c, -kpart * s); }
        }
        q[((size_t)b * 256 + n) * 128 + d] = qo;
        k[((size_t)b * 256 + n) * 128 + d] = ko;
    } else {
        int c0 = (part - 1) * 5;
#pragma unroll
        for (int j = 0; j < 5; ++j) {
            int c = c0 + j;
            float a = bv[c];
#pragma unroll
            for (int t = 0; t < 15; ++t) a = fmaf(hv[t], Wv[c * 15 + t], a);
            v[(((size_t)b * 15 + c) * 256 + n) * 128 + d] = a;
        }
    }
}

__global__ __launch_bounds__(512) void attn_k(const float* __restrict__ hin,
                                              const float* __restrict__ q,
                                              const float* __restrict__ k,
                                              const float* __restrict__ v,
                                              const float* __restrict__ gptr,
                                              float* __restrict__ hout) {
    __shared__ float klds[128];
    __shared__ float vlds[15][128];
    int bb = blockIdx.x >> 8, hh = blockIdx.x & 255;
    int tid = threadIdx.x;
    int w = tid & 127, cg = tid >> 7;
    const float* kb = k + (size_t)bb * 32768;
    const float* vb = v + (size_t)bb * 491520;
    for (int e = tid; e < 1920; e += 512) {
        int c = e >> 7, u = e & 127;
        vlds[c][u] = vb[(c * 256 + hh) * 128 + u];
    }
    if (tid < 128) klds[tid] = kb[hh * 128 + tid];
    float qs = q[((size_t)bb * 256 + hh) * 128 + w];
    __syncthreads();

    float m = -3.4e38f;
    for (int g = 0; g < 256; ++g) {
        float lg = qs * kb[g * 128 + w];
        if (g != hh) m = fmaxf(m, lg);
    }
#pragma unroll 8
    for (int u = 0; u < 128; ++u)
        m = fmaxf(m, qs * klds[u]);

    int c0 = cg * 4;
    int nc = (cg == 3) ? 3 : 4;
    float S = 0.f;
    float acc[4] = {0.f, 0.f, 0.f, 0.f};
    for (int g = 0; g < 256; ++g) {
        if (g == hh) continue;
        float p = __expf(fmaf(qs, kb[g * 128 + w], -m));
        S += p;
        const float* vg = vb + (size_t)(c0 * 256 + g) * 128 + w;
#pragma unroll
        for (int j = 0; j < 4; ++j)
            if (j < nc) acc[j] = fmaf(p, vg[(size_t)j * 32768], acc[j]);
    }
#pragma unroll 4
    for (int u = 0; u < 128; ++u) {
        float p = __expf(fmaf(qs, klds[u], -m));
        S += p;
#pragma unroll
        for (int j = 0; j < 4; ++j)
            if (j < nc) acc[j] = fmaf(p, vlds[c0 + j][u], acc[j]);
    }
    float scale = gptr[0] / S;
#pragma unroll
    for (int j = 0; j < 4; ++j) {
        if (j < nc) {
            size_t idx = (((size_t)bb * 15 + c0 + j) * 256 + hh) * 128 + w;
            hout[idx] = fmaf(scale, acc[j], hin[idx]);
        }
    }
}

extern "C" void kernel_launch(void* const* d_in, const int* in_sizes, int n_in,
                              void* d_out, int out_size, void* d_ws, size_t ws_size,
                              hipStream_t stream) {
    const float* x    = (const float*)d_in[0];
    const float* Wemb = (const float*)d_in[1];
    const float* bemb = (const float*)d_in[2];
    const float* Wq   = (const float*)d_in[3];
    const float* bq   = (const float*)d_in[4];
    const float* Wk   = (const float*)d_in[5];
    const float* bk   = (const float*)d_in[6];
    const float* Wv   = (const float*)d_in[7];
    const float* bv   = (const float*)d_in[8];
    const float* gam  = (const float*)d_in[9];
    const float* Wmlp = (const float*)d_in[10];
    const float* Wp1  = (const float*)d_in[11];
    const float* bp1  = (const float*)d_in[12];
    const float* Wp2  = (const float*)d_in[13];
    const float* bp2  = (const float*)d_in[14];

    float* out = (float*)d_out;
    float* xe  = out + XE_OFF;
    float* xh  = out + XH_OFF;
    float* xp  = out + XP_OFF;
    float* xhp = out + XHP_OFF;

    float* scr   = xhp;
    float* cosb  = scr + SCR_COS;
    float* sinb  = scr + SCR_SIN;
    float* qb    = scr + SCR_Q;
    float* kb    = scr + SCR_K;
    float* vb    = scr + SCR_V;
    float* ha    = scr + SCR_HA;
    float* hb    = scr + SCR_HB;
    float* prt   = scr + SCR_PART;
    u16*   Wembt = (u16*)(scr + SCR_WEMBT);
    u16*   Wp1t  = (u16*)(scr + SCR_WP1T);
    u16*   Wmlpt = (u16*)(scr + SCR_WMLPT);
    u16*   zb    = (u16*)d_ws;                          // 983040 bf16
    u16*   Wp2t  = (u16*)((char*)d_ws + 2097152);       // 524288 bf16

    rope_tab_k<<<32, 256, 0, stream>>>(cosb, sinb);
    tcvt_k<<<dim3(4, 128), 256, 0, stream>>>(Wemb, Wembt, 4096, 128);
    tcvt_k<<<dim3(4, 4), 256, 0, stream>>>(Wp1, Wp1t, 128, 128);
    tcvt_k<<<dim3(4, 4), 256, 0, stream>>>(Wmlp, Wmlpt, 128, 128);
    tcvt_k<<<dim3(128, 4), 256, 0, stream>>>(Wp2, Wp2t, 128, 4096);

    embed_mfma_k<<<dim3(8, 120), 256, 0, stream>>>(x, Wembt, prt);
    embed_reduce_k<<<960, 256, 0, stream>>>(prt, bemb, xe);

    const float* hin = xe;
    float* houts[3] = {ha, hb, ha};
    for (int i = 0; i < 3; ++i) {
        qkv_k<<<2048, 128, 0, stream>>>(hin, Wq + i * 15, bq + i, Wk + i * 15, bk + i,
                                        Wv + i * 225, bv + i * 15, cosb, sinb, qb, kb, vb);
        attn_k<<<512, 512, 0, stream>>>(hin, qb, kb, vb, gam + i, houts[i]);
        hin = houts[i];
    }

    gemm_bt_k<0, 0, 0><<<dim3(1, 120), 256, 0, stream>>>(hin, Wmlpt, nullptr, xh, 128);
    gemm_bt_k<0, 1, 1><<<dim3(1, 120), 256, 0, stream>>>(xe, Wp1t, bp1, zb, 128);
    gemm_bt_k<1, 0, 1><<<dim3(32, 120), 256, 0, stream>>>(zb, Wp2t, bp2, xp, 4096);
    gemm_bt_k<0, 1, 1><<<dim3(1, 120), 256, 0, stream>>>(xh, Wp1t, bp1, zb, 128);
    gemm_bt_k<1, 0, 1><<<dim3(32, 120), 256, 0, stream>>>(zb, Wp2t, bp2, xhp, 4096);
}

// Round 4
// 316.125 us; speedup vs baseline: 4.2933x; 2.8572x over previous
//
#include <hip/hip_runtime.h>
#include <math.h>

typedef __attribute__((ext_vector_type(8))) short bf16x8;
typedef __attribute__((ext_vector_type(8))) unsigned short u16x8;
typedef __attribute__((ext_vector_type(4))) float f32x4;
typedef unsigned short u16;

// Shapes: b=2, T=15, Hn=256, D=128, P=64, PPP=4096, REC=3
// d_out layout (f32): x_e[983040] | x_h[983040] | x_p[31457280] | x_h_p[31457280]
#define XE_OFF   0
#define XH_OFF   983040
#define XP_OFF   1966080
#define XHP_OFF  33423360

// scratch (float offsets) inside x_h_p region — all dead before the final gemm
#define SCR_COS   0         // 8192
#define SCR_SIN   8192      // 8192
#define SCR_Q     16384     // 65536  q[b][n][d]
#define SCR_K     81920     // 65536  kT[b][d][g]
#define SCR_V     147456    // 983040 vT[b][c][d][g]
#define SCR_HA    1130496   // 983040
#define SCR_HB    2113536   // 983040 (ends 3096576)
#define SCR_PART  4194304   // 8 x 983040 = 7864320 (ends 12058624)
#define SCR_WEMBT 12582912  // 524288 u16 = 262144 f (ends 12845056)
#define SCR_WP1T  12845056  // 16384 u16
#define SCR_WMLPT 12853248  // 16384 u16 (ends 12861440)
#define SCR_M1    13000704  // 65536  m1T[b][w][h]
#define SCR_S1    13066240  // 65536  S1T[b][w][h]
#define SCR_AW    13131776  // 983040 accWT[b][c][w][h] (ends 14114816)
// d_ws layout (bytes): [0..1966080) z_bf16 ; [2097152..3145728) Wp2t_bf16

__device__ __forceinline__ u16 f2bf(float f) {
    unsigned u = __float_as_uint(f);
    return (u16)((u + 0x7fffu + ((u >> 16) & 1)) >> 16);
}

union U8 { u16 h[8]; bf16x8 v; u16x8 u; };

__global__ __launch_bounds__(256) void rope_tab_k(float* __restrict__ cosb,
                                                  float* __restrict__ sinb) {
    int i = blockIdx.x * 256 + threadIdx.x;   // 8192 = 256 pos x 32 j
    int n = i >> 5, j = i & 31;
    float inv = expf(-(float)j * 0.28782313662425573f);  // 10000^(-2j/64)
    float ang = (float)n * inv;
    cosb[i] = cosf(ang);
    sinb[i] = sinf(ang);
}

// transpose + f32->bf16: out[N][K] = cvt(in[K][N]). grid = (N/32, K/32), block 256.
__global__ __launch_bounds__(256) void tcvt_k(const float* __restrict__ in,
                                              u16* __restrict__ out, int K, int N) {
    __shared__ float tl[32][33];
    int n0 = blockIdx.x * 32, k0 = blockIdx.y * 32;
    int tx = threadIdx.x & 31, ty = threadIdx.x >> 5;
#pragma unroll
    for (int r = 0; r < 4; ++r)
        tl[ty + r * 8][tx] = in[(size_t)(k0 + ty + r * 8) * N + n0 + tx];
    __syncthreads();
#pragma unroll
    for (int r = 0; r < 4; ++r)
        out[(size_t)(n0 + ty + r * 8) * K + k0 + tx] = f2bf(tl[tx][ty + r * 8]);
}

// ---------------- embed: MFMA bf16, split-K x8 ----------------
__global__ __launch_bounds__(256) void embed_mfma_k(const float* __restrict__ x,
                                                    const u16* __restrict__ Wembt,
                                                    float* __restrict__ part) {
    __shared__ char Al[64 * 128];    // [row][k] bf16, swizzled
    __shared__ char Bl[128 * 128];   // [n][k] bf16, swizzled
    int ck = blockIdx.x, mt = blockIdx.y;
    int m0 = mt * 64;
    int bt = m0 >> 8;
    int n0r = m0 & 255;
    const float* xb = x + (size_t)bt * 1048576;
    int tid = threadIdx.x;
    int ln = tid & 63, wv = tid >> 6;
    int wm = wv >> 1, wn = wv & 1;

    f32x4 zero4 = {0.f, 0.f, 0.f, 0.f};
    f32x4 acc[2][4];
#pragma unroll
    for (int mi = 0; mi < 2; ++mi)
#pragma unroll
        for (int ni = 0; ni < 4; ++ni) acc[mi][ni] = zero4;

    int ar = tid & 63, aseg = tid >> 6;
    int an = n0r + ar;
    const float* arow = xb + ((size_t)(an >> 4) * 64) * 1024 + (an & 15) * 64;

    for (int bk = 0; bk < 8; ++bk) {
        int kbase = ck * 512 + bk * 64;
        __syncthreads();
        {
            const float* src = arow + (size_t)(kbase >> 6) * 1024 + aseg * 16;
            float4 f0 = ((const float4*)src)[0];
            float4 f1 = ((const float4*)src)[1];
            float4 f2 = ((const float4*)src)[2];
            float4 f3 = ((const float4*)src)[3];
            U8 u0, u1;
            u0.h[0] = f2bf(f0.x); u0.h[1] = f2bf(f0.y); u0.h[2] = f2bf(f0.z); u0.h[3] = f2bf(f0.w);
            u0.h[4] = f2bf(f1.x); u0.h[5] = f2bf(f1.y); u0.h[6] = f2bf(f1.z); u0.h[7] = f2bf(f1.w);
            u1.h[0] = f2bf(f2.x); u1.h[1] = f2bf(f2.y); u1.h[2] = f2bf(f2.z); u1.h[3] = f2bf(f2.w);
            u1.h[4] = f2bf(f3.x); u1.h[5] = f2bf(f3.y); u1.h[6] = f2bf(f3.z); u1.h[7] = f2bf(f3.w);
            int sw = (ar & 7) << 4;
            *(bf16x8*)(Al + ar * 128 + ((aseg * 32) ^ sw))      = u0.v;
            *(bf16x8*)(Al + ar * 128 + ((aseg * 32 + 16) ^ sw)) = u1.v;
        }
#pragma unroll
        for (int j = 0; j < 4; ++j) {
            int c = tid + 256 * j;
            int n = c >> 3, k0 = (c & 7) * 8;
            U8 u;
            u.u = *(const u16x8*)(Wembt + (size_t)n * 4096 + kbase + k0);
            *(bf16x8*)(Bl + n * 128 + ((k0 * 2) ^ ((n & 7) << 4))) = u.v;
        }
        __syncthreads();
#pragma unroll
        for (int ks = 0; ks < 2; ++ks) {
            int k2 = (ks * 32 + (ln >> 4) * 8) * 2;
            bf16x8 a[2], b[4];
#pragma unroll
            for (int mi = 0; mi < 2; ++mi) {
                int row = wm * 32 + mi * 16 + (ln & 15);
                a[mi] = *(const bf16x8*)(Al + row * 128 + (k2 ^ ((row & 7) << 4)));
            }
#pragma unroll
            for (int ni = 0; ni < 4; ++ni) {
                int n = wn * 64 + ni * 16 + (ln & 15);
                b[ni] = *(const bf16x8*)(Bl + n * 128 + (k2 ^ ((n & 7) << 4)));
            }
#pragma unroll
            for (int mi = 0; mi < 2; ++mi)
#pragma unroll
                for (int ni = 0; ni < 4; ++ni)
                    acc[mi][ni] = __builtin_amdgcn_mfma_f32_16x16x32_bf16(a[mi], b[ni], acc[mi][ni], 0, 0, 0);
        }
    }
    float* p = part + (size_t)ck * 983040;
#pragma unroll
    for (int mi = 0; mi < 2; ++mi)
#pragma unroll
        for (int ni = 0; ni < 4; ++ni)
#pragma unroll
            for (int r = 0; r < 4; ++r) {
                int row = m0 + wm * 32 + mi * 16 + (ln >> 4) * 4 + r;
                int col = wn * 64 + ni * 16 + (ln & 15);
                p[(size_t)row * 128 + col] = acc[mi][ni][r];
            }
}

// xe = sum of 8 parts + bias. grid 960, block 256, float4.
__global__ __launch_bounds__(256) void embed_reduce_k(const float* __restrict__ part,
                                                      const float* __restrict__ bemb,
                                                      float* __restrict__ xe) {
    int i = blockIdx.x * 256 + threadIdx.x;
    const float4* p = (const float4*)part;
    float4 s = p[i];
#pragma unroll
    for (int j = 1; j < 8; ++j) {
        float4 a = p[(size_t)j * 245760 + i];
        s.x += a.x; s.y += a.y; s.z += a.z; s.w += a.w;
    }
    float4 bb = ((const float4*)bemb)[i & 31];
    s.x += bb.x; s.y += bb.y; s.z += bb.z; s.w += bb.w;
    ((float4*)xe)[i] = s;
}

// ---------------- generic K=128 MFMA GEMM ----------------
template<int ABF, int OBF, int HASB>
__global__ __launch_bounds__(256) void gemm_bt_k(const void* __restrict__ Ap,
                                                 const u16* __restrict__ Bt,
                                                 const float* __restrict__ bias,
                                                 void* __restrict__ outp, int N) {
    __shared__ char Al[64 * 256];
    __shared__ char Bl[128 * 256];
    int n0 = blockIdx.x * 128, m0 = blockIdx.y * 64;
    int tid = threadIdx.x;
    int ln = tid & 63, wv = tid >> 6;
    int wm = wv >> 1, wn = wv & 1;

    {
        int row = tid >> 2, kseg = (tid & 3) * 32;
        int sw = (row & 7) << 4;
        if (ABF) {
            const u16* src = (const u16*)Ap + (size_t)(m0 + row) * 128 + kseg;
#pragma unroll
            for (int j = 0; j < 4; ++j) {
                U8 u; u.u = *(const u16x8*)(src + j * 8);
                *(bf16x8*)(Al + row * 256 + (((kseg + j * 8) * 2) ^ sw)) = u.v;
            }
        } else {
            const float* src = (const float*)Ap + (size_t)(m0 + row) * 128 + kseg;
#pragma unroll
            for (int j = 0; j < 4; ++j) {
                float4 f0 = ((const float4*)src)[2 * j];
                float4 f1 = ((const float4*)src)[2 * j + 1];
                U8 u;
                u.h[0] = f2bf(f0.x); u.h[1] = f2bf(f0.y); u.h[2] = f2bf(f0.z); u.h[3] = f2bf(f0.w);
                u.h[4] = f2bf(f1.x); u.h[5] = f2bf(f1.y); u.h[6] = f2bf(f1.z); u.h[7] = f2bf(f1.w);
                *(bf16x8*)(Al + row * 256 + (((kseg + j * 8) * 2) ^ sw)) = u.v;
            }
        }
    }
    {
        int n = tid >> 1, kseg = (tid & 1) * 64;
        int sw = (n & 7) << 4;
        const u16* src = Bt + (size_t)(n0 + n) * 128 + kseg;
#pragma unroll
        for (int j = 0; j < 8; ++j) {
            U8 u; u.u = *(const u16x8*)(src + j * 8);
            *(bf16x8*)(Bl + n * 256 + (((kseg + j * 8) * 2) ^ sw)) = u.v;
        }
    }
    __syncthreads();

    f32x4 zero4 = {0.f, 0.f, 0.f, 0.f};
    f32x4 acc[2][4];
#pragma unroll
    for (int mi = 0; mi < 2; ++mi)
#pragma unroll
        for (int ni = 0; ni < 4; ++ni) acc[mi][ni] = zero4;

#pragma unroll
    for (int ks = 0; ks < 4; ++ks) {
        int k2 = (ks * 32 + (ln >> 4) * 8) * 2;
        bf16x8 a[2], b[4];
#pragma unroll
        for (int mi = 0; mi < 2; ++mi) {
            int row = wm * 32 + mi * 16 + (ln & 15);
            a[mi] = *(const bf16x8*)(Al + row * 256 + (k2 ^ ((row & 7) << 4)));
        }
#pragma unroll
        for (int ni = 0; ni < 4; ++ni) {
            int n = wn * 64 + ni * 16 + (ln & 15);
            b[ni] = *(const bf16x8*)(Bl + n * 256 + (k2 ^ ((n & 7) << 4)));
        }
#pragma unroll
        for (int mi = 0; mi < 2; ++mi)
#pragma unroll
            for (int ni = 0; ni < 4; ++ni)
                acc[mi][ni] = __builtin_amdgcn_mfma_f32_16x16x32_bf16(a[mi], b[ni], acc[mi][ni], 0, 0, 0);
    }

#pragma unroll
    for (int mi = 0; mi < 2; ++mi)
#pragma unroll
        for (int ni = 0; ni < 4; ++ni)
#pragma unroll
            for (int r = 0; r < 4; ++r) {
                int row = m0 + wm * 32 + mi * 16 + (ln >> 4) * 4 + r;
                int col = n0 + wn * 64 + ni * 16 + (ln & 15);
                float v = acc[mi][ni][r];
                if (HASB) v += bias[col];
                if (OBF) ((u16*)outp)[(size_t)row * N + col] = f2bf(v);
                else     ((float*)outp)[(size_t)row * N + col] = v;
            }
}

// ---------------- attention, W part + fused qkv. grid = b*256 (b,n), block 128 (=d) ----
// Computes q (RoPE), k-row, v-rows; writes q row-major, kT/vT transposed;
// W-part softmax partials with safe upper-bound max m1 = |q|*max|k_row|.
__global__ __launch_bounds__(128) void attnW_k(const float* __restrict__ hin,
    const float* __restrict__ Wq, const float* __restrict__ bq,
    const float* __restrict__ Wk, const float* __restrict__ bk,
    const float* __restrict__ Wv, const float* __restrict__ bv,
    const float* __restrict__ cosb, const float* __restrict__ sinb,
    float* __restrict__ q, float* __restrict__ kT, float* __restrict__ vT,
    float* __restrict__ m1T, float* __restrict__ S1T, float* __restrict__ accWT) {
    __shared__ float klds[128];
    __shared__ float vlds[128][20];   // [u][c], padded to 20 for aligned b128 reads
    __shared__ float red[2];
    int b = blockIdx.x >> 8, n = blockIdx.x & 255;
    int d = threadIdx.x;
    float hv[15];
#pragma unroll
    for (int t = 0; t < 15; ++t)
        hv[t] = hin[(((size_t)b * 15 + t) * 256 + n) * 128 + d];

    float qp = bq[0], kp = bk[0];
#pragma unroll
    for (int t = 0; t < 15; ++t) {
        qp = fmaf(hv[t], Wq[t], qp);
        kp = fmaf(hv[t], Wk[t], kp);
    }
    float qpart = __shfl_xor(qp, 1);
    float kpart = __shfl_xor(kp, 1);
    float qo = qp, ko = kp;
    if (d < 64) {
        int j = d >> 1;
        float c = cosb[n * 32 + j], s = sinb[n * 32 + j];
        if (d & 1) { qo = fmaf(qp, c,  qpart * s); ko = fmaf(kp, c,  kpart * s); }
        else       { qo = fmaf(qp, c, -qpart * s); ko = fmaf(kp, c, -kpart * s); }
    }
    float vv[15];
#pragma unroll
    for (int c = 0; c < 15; ++c) {
        float a = bv[c];
#pragma unroll
        for (int t = 0; t < 15; ++t) a = fmaf(hv[t], Wv[c * 15 + t], a);
        vv[c] = a;
    }
    // global writes (q coalesced; kT/vT scattered one-time)
    q[((size_t)b * 256 + n) * 128 + d] = qo;
    kT[((size_t)b * 128 + d) * 256 + n] = ko;
#pragma unroll
    for (int c = 0; c < 15; ++c)
        vT[(((size_t)b * 15 + c) * 128 + d) * 256 + n] = vv[c];

    // LDS stage
    klds[d] = ko;
#pragma unroll
    for (int c = 0; c < 15; ++c) vlds[d][c] = vv[c];
    // |k| row max (2 waves)
    float ka = fabsf(ko);
#pragma unroll
    for (int off = 32; off >= 1; off >>= 1) ka = fmaxf(ka, __shfl_xor(ka, off));
    if ((d & 63) == 0) red[d >> 6] = ka;
    __syncthreads();
    ka = fmaxf(red[0], red[1]);

    float m1 = fabsf(qo) * ka;       // >= all logits q*k_row[u]
    float S1 = 0.f;
    float acc[15];
#pragma unroll
    for (int c = 0; c < 15; ++c) acc[c] = 0.f;
#pragma unroll 2
    for (int u4 = 0; u4 < 128; u4 += 4) {
        float k4a[4];
        *(float4*)k4a = *(const float4*)&klds[u4];
#pragma unroll
        for (int i = 0; i < 4; ++i) {
            float p = __expf(fmaf(qo, k4a[i], -m1));
            S1 += p;
            float va[16];
            *(float4*)&va[0]  = *(const float4*)&vlds[u4 + i][0];
            *(float4*)&va[4]  = *(const float4*)&vlds[u4 + i][4];
            *(float4*)&va[8]  = *(const float4*)&vlds[u4 + i][8];
            *(float4*)&va[12] = *(const float4*)&vlds[u4 + i][12];
#pragma unroll
            for (int c = 0; c < 15; ++c) acc[c] = fmaf(p, va[c], acc[c]);
        }
    }
    size_t tix = ((size_t)b * 128 + d) * 256 + n;
    m1T[tix] = m1;
    S1T[tix] = S1;
#pragma unroll
    for (int c = 0; c < 15; ++c)
        accWT[(((size_t)b * 15 + c) * 128 + d) * 256 + n] = acc[c];
}

// ---------------- attention, H part + combine + residual. grid = b*128 (b,w), block 256 (=h) --
__global__ __launch_bounds__(256) void attnH_k(const float* __restrict__ hin,
    const float* __restrict__ q, const float* __restrict__ kT, const float* __restrict__ vT,
    const float* __restrict__ m1T, const float* __restrict__ S1T, const float* __restrict__ accWT,
    const float* __restrict__ gptr, float* __restrict__ hout) {
    __shared__ float klds[256];
    __shared__ float vgl[256][20];    // [g][c], padded
    __shared__ float kabslds;
    int b = blockIdx.x >> 7, w = blockIdx.x & 127;
    int tid = threadIdx.x;            // = h
    // stage k column (contiguous in kT)
    if (tid < 64) {
        float4 kk = *(const float4*)(kT + ((size_t)b * 128 + w) * 256 + 4 * tid);
        *(float4*)&klds[4 * tid] = kk;
        float ka = fmaxf(fmaxf(fabsf(kk.x), fabsf(kk.y)), fmaxf(fabsf(kk.z), fabsf(kk.w)));
#pragma unroll
        for (int off = 32; off >= 1; off >>= 1) ka = fmaxf(ka, __shfl_xor(ka, off));
        if (tid == 0) kabslds = ka;
    }
    // stage v columns (contiguous in vT): 960 float4 over 1024 slots
#pragma unroll
    for (int j = 0; j < 4; ++j) {
        int e = tid + 256 * j;
        int c = e & 15, g4 = e >> 4;
        if (c < 15) {
            float4 vv = *(const float4*)(vT + (((size_t)b * 15 + c) * 128 + w) * 256 + 4 * g4);
            vgl[4 * g4 + 0][c] = vv.x;
            vgl[4 * g4 + 1][c] = vv.y;
            vgl[4 * g4 + 2][c] = vv.z;
            vgl[4 * g4 + 3][c] = vv.w;
        }
    }
    float qs = q[((size_t)b * 256 + tid) * 128 + w];
    __syncthreads();

    float m2 = fabsf(qs) * kabslds;   // >= all logits q*k_col[g]
    float S2 = 0.f;
    float acc[15];
#pragma unroll
    for (int c = 0; c < 15; ++c) acc[c] = 0.f;
    for (int g4 = 0; g4 < 256; g4 += 4) {
        float k4a[4];
        *(float4*)k4a = *(const float4*)&klds[g4];
#pragma unroll
        for (int i = 0; i < 4; ++i) {
            int g = g4 + i;
            float p = __expf(fmaf(qs, k4a[i], -m2));
            p = (g == tid) ? 0.f : p;     // diag mask
            S2 += p;
            float va[16];
            *(float4*)&va[0]  = *(const float4*)&vgl[g][0];
            *(float4*)&va[4]  = *(const float4*)&vgl[g][4];
            *(float4*)&va[8]  = *(const float4*)&vgl[g][8];
            *(float4*)&va[12] = *(const float4*)&vgl[g][12];
#pragma unroll
            for (int c = 0; c < 15; ++c) acc[c] = fmaf(p, va[c], acc[c]);
        }
    }
    // combine with W part + residual
    size_t tix = ((size_t)b * 128 + w) * 256 + tid;
    float m1 = m1T[tix], S1v = S1T[tix];
    float mm = fmaxf(m1, m2);
    float e1 = __expf(m1 - mm), e2 = __expf(m2 - mm);
    float sc = gptr[0] / (S1v * e1 + S2 * e2);
#pragma unroll
    for (int c = 0; c < 15; ++c) {
        float aw = accWT[(((size_t)b * 15 + c) * 128 + w) * 256 + tid];
        size_t oi = (((size_t)b * 15 + c) * 256 + tid) * 128 + w;
        hout[oi] = fmaf((aw * e1 + acc[c] * e2), sc, hin[oi]);
    }
}

extern "C" void kernel_launch(void* const* d_in, const int* in_sizes, int n_in,
                              void* d_out, int out_size, void* d_ws, size_t ws_size,
                              hipStream_t stream) {
    const float* x    = (const float*)d_in[0];
    const float* Wemb = (const float*)d_in[1];
    const float* bemb = (const float*)d_in[2];
    const float* Wq   = (const float*)d_in[3];
    const float* bq   = (const float*)d_in[4];
    const float* Wk   = (const float*)d_in[5];
    const float* bk   = (const float*)d_in[6];
    const float* Wv   = (const float*)d_in[7];
    const float* bv   = (const float*)d_in[8];
    const float* gam  = (const float*)d_in[9];
    const float* Wmlp = (const float*)d_in[10];
    const float* Wp1  = (const float*)d_in[11];
    const float* bp1  = (const float*)d_in[12];
    const float* Wp2  = (const float*)d_in[13];
    const float* bp2  = (const float*)d_in[14];

    float* out = (float*)d_out;
    float* xe  = out + XE_OFF;
    float* xh  = out + XH_OFF;
    float* xp  = out + XP_OFF;
    float* xhp = out + XHP_OFF;

    float* scr   = xhp;
    float* cosb  = scr + SCR_COS;
    float* sinb  = scr + SCR_SIN;
    float* qb    = scr + SCR_Q;
    float* kTb   = scr + SCR_K;
    float* vTb   = scr + SCR_V;
    float* ha    = scr + SCR_HA;
    float* hb    = scr + SCR_HB;
    float* prt   = scr + SCR_PART;
    float* m1T   = scr + SCR_M1;
    float* S1T   = scr + SCR_S1;
    float* accWT = scr + SCR_AW;
    u16*   Wembt = (u16*)(scr + SCR_WEMBT);
    u16*   Wp1t  = (u16*)(scr + SCR_WP1T);
    u16*   Wmlpt = (u16*)(scr + SCR_WMLPT);
    u16*   zb    = (u16*)d_ws;
    u16*   Wp2t  = (u16*)((char*)d_ws + 2097152);

    rope_tab_k<<<32, 256, 0, stream>>>(cosb, sinb);
    tcvt_k<<<dim3(4, 128), 256, 0, stream>>>(Wemb, Wembt, 4096, 128);
    tcvt_k<<<dim3(4, 4), 256, 0, stream>>>(Wp1, Wp1t, 128, 128);
    tcvt_k<<<dim3(4, 4), 256, 0, stream>>>(Wmlp, Wmlpt, 128, 128);
    tcvt_k<<<dim3(128, 4), 256, 0, stream>>>(Wp2, Wp2t, 128, 4096);

    embed_mfma_k<<<dim3(8, 120), 256, 0, stream>>>(x, Wembt, prt);
    embed_reduce_k<<<960, 256, 0, stream>>>(prt, bemb, xe);

    const float* hin = xe;
    float* houts[3] = {ha, hb, ha};
    for (int i = 0; i < 3; ++i) {
        attnW_k<<<512, 128, 0, stream>>>(hin, Wq + i * 15, bq + i, Wk + i * 15, bk + i,
                                         Wv + i * 225, bv + i * 15, cosb, sinb,
                                         qb, kTb, vTb, m1T, S1T, accWT);
        attnH_k<<<256, 256, 0, stream>>>(hin, qb, kTb, vTb, m1T, S1T, accWT,
                                         gam + i, houts[i]);
        hin = houts[i];
    }

    gemm_bt_k<0, 0, 0><<<dim3(1, 120), 256, 0, stream>>>(hin, Wmlpt, nullptr, xh, 128);
    gemm_bt_k<0, 1, 1><<<dim3(1, 120), 256, 0, stream>>>(xe, Wp1t, bp1, zb, 128);
    gemm_bt_k<1, 0, 1><<<dim3(32, 120), 256, 0, stream>>>(zb, Wp2t, bp2, xp, 4096);
    gemm_bt_k<0, 1, 1><<<dim3(1, 120), 256, 0, stream>>>(xh, Wp1t, bp1, zb, 128);
    gemm_bt_k<1, 0, 1><<<dim3(32, 120), 256, 0, stream>>>(zb, Wp2t, bp2, xhp, 4096);
}